// Round 7
// baseline (395.129 us; speedup 1.0000x reference)
//
#include <hip/hip_runtime.h>

#define NN 100000
#define NE 200000
#define DN 128
#define DE 16
#define NR 3
#define NEDGE (NR * NE)         // 600000
#define NB1 98                  // scan1 blocks: 1024 elems each >= NN
#define KTOT 576                // 128 self + 3*128 rel + 64 (48 We + 16 pad)

typedef __attribute__((ext_vector_type(8))) short short8;
typedef __attribute__((ext_vector_type(4))) float f32x4;

__device__ __forceinline__ unsigned short f2bf(float f) {
    unsigned int u = __float_as_uint(f);
    u = (u + 0x7fffu + ((u >> 16) & 1u)) >> 16;   // RNE
    return (unsigned short)u;
}

// ---------------------------------------------------------------------------
// xb = bf16(x)
// ---------------------------------------------------------------------------
__global__ __launch_bounds__(256) void conv_x_kernel(
    const float* __restrict__ x, unsigned short* __restrict__ xb)
{
    const int i = blockIdx.x * 256 + threadIdx.x;   // float4 index, 3.2M total
    float4 v = ((const float4*)x)[i];
    ushort4 o;
    o.x = f2bf(v.x); o.y = f2bf(v.y); o.z = f2bf(v.z); o.w = f2bf(v.w);
    ((ushort4*)xb)[i] = o;
}

// ---------------------------------------------------------------------------
// Wtall[n][kg] = bf16 of the concatenated weight matrix, n-major (576 k per n):
//   kg 0..127   : W_self[k][n]
//   kg 128..511 : W_rel[r][k][n]   r = (kg-128)/128
//   kg 512..559 : We_rel[r][k][n]  r = (kg-512)/16
//   kg 560..575 : 0 (pad)
// ---------------------------------------------------------------------------
__global__ __launch_bounds__(256) void conv_w_kernel(
    const float* __restrict__ W_self, const float* __restrict__ W_rel,
    const float* __restrict__ We_rel, unsigned short* __restrict__ Wtall)
{
    const int id = blockIdx.x * 256 + threadIdx.x;  // 128*576 = 73728
    if (id >= 128 * KTOT) return;
    const int n = id / KTOT, kg = id % KTOT;
    float v = 0.f;
    if (kg < 128)       v = W_self[kg * 128 + n];
    else if (kg < 512)  v = W_rel[(size_t)(kg - 128) * 128 + n];          // r*16384 + k*128
    else if (kg < 560)  v = We_rel[(size_t)(kg - 512) * 128 + n];         // r*2048 + k*128
    Wtall[id] = f2bf(v);
}

// ---------------------------------------------------------------------------
// CSR build keyed by dst.
// ---------------------------------------------------------------------------
__global__ __launch_bounds__(256) void hist_kernel(
    const int* __restrict__ ei, unsigned* __restrict__ cur)
{
    const int eid = blockIdx.x * 256 + threadIdx.x;
    if (eid < NEDGE) atomicAdd(&cur[ei[2 * eid + 1]], 1u);
}

__global__ __launch_bounds__(256) void scan1_kernel(
    const unsigned* __restrict__ cnt, unsigned* __restrict__ offs,
    unsigned* __restrict__ bsum)
{
    __shared__ unsigned wtot[4];
    const int tid = threadIdx.x, lane = tid & 63, wv = tid >> 6;
    const int base = blockIdx.x * 1024 + tid * 4;
    unsigned c[4];
    #pragma unroll
    for (int j = 0; j < 4; ++j) c[j] = (base + j < NN) ? cnt[base + j] : 0u;
    const unsigned ts = c[0] + c[1] + c[2] + c[3];
    unsigned incl = ts;
    #pragma unroll
    for (int d = 1; d < 64; d <<= 1) {
        unsigned v = __shfl_up(incl, d, 64);
        if (lane >= d) incl += v;
    }
    if (lane == 63) wtot[wv] = incl;
    __syncthreads();
    unsigned woff = 0;
    for (int p = 0; p < 4; ++p) if (p < wv) woff += wtot[p];
    unsigned run = woff + incl - ts;
    #pragma unroll
    for (int j = 0; j < 4; ++j) {
        if (base + j < NN) offs[base + j] = run;
        run += c[j];
    }
    if (tid == 255) bsum[blockIdx.x] = woff + incl;
}

__global__ void scan2_kernel(unsigned* __restrict__ bsum)
{
    const int lane = threadIdx.x;   // 64
    unsigned v[2], s = 0;
    const int base = lane * 2;
    #pragma unroll
    for (int j = 0; j < 2; ++j) {
        v[j] = (base + j < NB1) ? bsum[base + j] : 0u;
        s += v[j];
    }
    unsigned incl = s;
    #pragma unroll
    for (int d = 1; d < 64; d <<= 1) {
        unsigned t = __shfl_up(incl, d, 64);
        if (lane >= d) incl += t;
    }
    unsigned run = incl - s;
    #pragma unroll
    for (int j = 0; j < 2; ++j) {
        if (base + j < NB1) bsum[base + j] = run;
        run += v[j];
    }
}

__global__ __launch_bounds__(256) void scan3_kernel(
    unsigned* __restrict__ offs, unsigned* __restrict__ cur,
    const unsigned* __restrict__ bsum)
{
    const int base = blockIdx.x * 1024 + threadIdx.x * 4;
    const unsigned add = bsum[blockIdx.x];
    #pragma unroll
    for (int j = 0; j < 4; ++j) {
        if (base + j < NN) {
            unsigned v = offs[base + j] + add;
            offs[base + j] = v;
            cur[base + j]  = v;
        }
    }
    if (blockIdx.x == 0 && threadIdx.x == 0) offs[NN] = NEDGE;
}

__global__ __launch_bounds__(256) void fill_kernel(
    const int* __restrict__ ei, unsigned* __restrict__ cur,
    uint2* __restrict__ elist)
{
    const int eid = blockIdx.x * 256 + threadIdx.x;
    if (eid < NEDGE) {
        const unsigned src = (unsigned)ei[2 * eid + 0];
        const int dst = ei[2 * eid + 1];
        const unsigned pos = atomicAdd(&cur[dst], 1u);
        elist[pos] = make_uint2(src, (unsigned)eid);
    }
}

// ---------------------------------------------------------------------------
// Pass A: per dst, accumulate raw features per relation. Zero LDS -> 32 w/CU.
//   Sb[dst][r][0:128]  = sum_{e: rel r} xb[src_e]      (bf16)
//   eagg[dst][r*16+k]  = sum_{e: rel r} edge_attr[e,k] (bf16, [48:64) = 0)
// One wave per dst, 2 cols/lane (packed dword), edge loop unrolled 4x.
// NOTE: ea* are FULL sums replicated across the 4 lane-groups (every lane
// walks every edge) — write directly from lanes<16, do NOT reduce (round-6
// bug: shfl_xor reduction quadrupled them).
// ---------------------------------------------------------------------------
__global__ __launch_bounds__(256) void aggregate_kernel(
    const unsigned short* __restrict__ xb,
    const float* __restrict__ edge_attr,
    const unsigned* __restrict__ offs,
    const uint2* __restrict__ elist,
    unsigned short* __restrict__ Sb,
    unsigned short* __restrict__ eagg)
{
    const int tid = threadIdx.x;
    const int wv = tid >> 6, lane = tid & 63;
    const int dst = blockIdx.x * 4 + wv;          // grid 25000, exact
    const int col = 2 * lane;
    const int k16 = lane & 15;

    const unsigned s = offs[dst];
    const unsigned e = offs[dst + 1];

    float s00 = 0.f, s01 = 0.f, s10 = 0.f, s11 = 0.f, s20 = 0.f, s21 = 0.f;
    float ea0 = 0.f, ea1 = 0.f, ea2 = 0.f;

    unsigned i = s;
    for (; i + 4 <= e; i += 4) {
        const uint2 p0 = elist[i],     p1 = elist[i + 1];
        const uint2 p2 = elist[i + 2], p3 = elist[i + 3];
        const unsigned v0 = *(const unsigned*)(xb + (size_t)p0.x * 128 + col);
        const unsigned v1 = *(const unsigned*)(xb + (size_t)p1.x * 128 + col);
        const unsigned v2 = *(const unsigned*)(xb + (size_t)p2.x * 128 + col);
        const unsigned v3 = *(const unsigned*)(xb + (size_t)p3.x * 128 + col);
        const float a0 = edge_attr[(size_t)p0.y * 16 + k16];
        const float a1 = edge_attr[(size_t)p1.y * 16 + k16];
        const float a2 = edge_attr[(size_t)p2.y * 16 + k16];
        const float a3 = edge_attr[(size_t)p3.y * 16 + k16];
        const unsigned vs[4] = {v0, v1, v2, v3};
        const float    as[4] = {a0, a1, a2, a3};
        const unsigned es[4] = {p0.y, p1.y, p2.y, p3.y};
        #pragma unroll
        for (int u = 0; u < 4; ++u) {
            const float f0 = __uint_as_float(vs[u] << 16);
            const float f1 = __uint_as_float(vs[u] & 0xffff0000u);
            const unsigned ru = __builtin_amdgcn_readfirstlane(es[u]);
            if (ru < NE)            { s00 += f0; s01 += f1; ea0 += as[u]; }
            else if (ru < 2u * NE)  { s10 += f0; s11 += f1; ea1 += as[u]; }
            else                    { s20 += f0; s21 += f1; ea2 += as[u]; }
        }
    }
    for (; i < e; ++i) {
        const uint2 p = elist[i];
        const unsigned v = *(const unsigned*)(xb + (size_t)p.x * 128 + col);
        const float a = edge_attr[(size_t)p.y * 16 + k16];
        const float f0 = __uint_as_float(v << 16);
        const float f1 = __uint_as_float(v & 0xffff0000u);
        const unsigned ru = __builtin_amdgcn_readfirstlane(p.y);
        if (ru < NE)            { s00 += f0; s01 += f1; ea0 += a; }
        else if (ru < 2u * NE)  { s10 += f0; s11 += f1; ea1 += a; }
        else                    { s20 += f0; s21 += f1; ea2 += a; }
    }

    // write S (packed 2 bf16 per dword, coalesced 256B per r)
    unsigned short* sr = Sb + (size_t)dst * 384;
    *(unsigned*)(sr + col)       = ((unsigned)f2bf(s01) << 16) | f2bf(s00);
    *(unsigned*)(sr + 128 + col) = ((unsigned)f2bf(s11) << 16) | f2bf(s10);
    *(unsigned*)(sr + 256 + col) = ((unsigned)f2bf(s21) << 16) | f2bf(s20);

    // ea* already hold the full segment sums (replicated per lane-group)
    unsigned short* ep = eagg + (size_t)dst * 64;
    if (lane < 16) {
        ep[lane]      = f2bf(ea0);
        ep[16 + lane] = f2bf(ea1);
        ep[32 + lane] = f2bf(ea2);
    } else if (lane < 32) {
        ep[32 + lane] = 0;          // pad [48:64) = 0
    }
}

// ---------------------------------------------------------------------------
// Pass B: LDS-free MFMA GEMM, K=576 over [xb | S0 S1 S2 | eagg] @ Wtall + b, relu.
// Wave handles 32 rows (two 16-row tiles sharing B fragments). No syncs.
// ---------------------------------------------------------------------------
__global__ __launch_bounds__(256) void gemm_out_kernel(
    const unsigned short* __restrict__ xb,
    const unsigned short* __restrict__ Sb,
    const unsigned short* __restrict__ eagg,
    const unsigned short* __restrict__ Wtall,
    const float* __restrict__ b,
    float* __restrict__ out)
{
    const int tid = threadIdx.x;
    const int wave = tid >> 6, lane = tid & 63;
    const int lm = lane & 15, lq = lane >> 4;
    const int mr = blockIdx.x * 128 + wave * 32;
    const int r0 = mr + lm, r1 = mr + 16 + lm;
    const int r0c = (r0 < NN) ? r0 : (NN - 1);
    const int r1c = (r1 < NN) ? r1 : (NN - 1);
    const int koff = lq * 8;

    const unsigned short* xp0 = xb   + (size_t)r0c * 128 + koff;
    const unsigned short* xp1 = xb   + (size_t)r1c * 128 + koff;
    const unsigned short* sp0 = Sb   + (size_t)r0c * 384 + koff;
    const unsigned short* sp1 = Sb   + (size_t)r1c * 384 + koff;
    const unsigned short* ep0 = eagg + (size_t)r0c * 64  + koff;
    const unsigned short* ep1 = eagg + (size_t)r1c * 64  + koff;
    const unsigned short* wp  = Wtall + (size_t)lm * KTOT + koff;

    f32x4 acc0[8], acc1[8];
    #pragma unroll
    for (int n = 0; n < 8; ++n) {
        acc0[n] = (f32x4){0.f, 0.f, 0.f, 0.f};
        acc1[n] = (f32x4){0.f, 0.f, 0.f, 0.f};
    }

    // segment 1: xb, kglob 0..127
    #pragma unroll
    for (int ks = 0; ks < 4; ++ks) {
        const short8 a0 = *(const short8*)(xp0 + ks * 32);
        const short8 a1 = *(const short8*)(xp1 + ks * 32);
        #pragma unroll
        for (int n = 0; n < 8; ++n) {
            const short8 bf = *(const short8*)(wp + (size_t)n * 16 * KTOT + ks * 32);
            acc0[n] = __builtin_amdgcn_mfma_f32_16x16x32_bf16(a0, bf, acc0[n], 0, 0, 0);
            acc1[n] = __builtin_amdgcn_mfma_f32_16x16x32_bf16(a1, bf, acc1[n], 0, 0, 0);
        }
    }
    // segment 2: S, kglob 128..511
    #pragma unroll
    for (int ks = 0; ks < 12; ++ks) {
        const short8 a0 = *(const short8*)(sp0 + ks * 32);
        const short8 a1 = *(const short8*)(sp1 + ks * 32);
        #pragma unroll
        for (int n = 0; n < 8; ++n) {
            const short8 bf = *(const short8*)(wp + (size_t)n * 16 * KTOT + 128 + ks * 32);
            acc0[n] = __builtin_amdgcn_mfma_f32_16x16x32_bf16(a0, bf, acc0[n], 0, 0, 0);
            acc1[n] = __builtin_amdgcn_mfma_f32_16x16x32_bf16(a1, bf, acc1[n], 0, 0, 0);
        }
    }
    // segment 3: eagg, kglob 512..575
    #pragma unroll
    for (int ks = 0; ks < 2; ++ks) {
        const short8 a0 = *(const short8*)(ep0 + ks * 32);
        const short8 a1 = *(const short8*)(ep1 + ks * 32);
        #pragma unroll
        for (int n = 0; n < 8; ++n) {
            const short8 bf = *(const short8*)(wp + (size_t)n * 16 * KTOT + 512 + ks * 32);
            acc0[n] = __builtin_amdgcn_mfma_f32_16x16x32_bf16(a0, bf, acc0[n], 0, 0, 0);
            acc1[n] = __builtin_amdgcn_mfma_f32_16x16x32_bf16(a1, bf, acc1[n], 0, 0, 0);
        }
    }

    #pragma unroll
    for (int n = 0; n < 8; ++n) {
        const float bias = b[n * 16 + lm];
        #pragma unroll
        for (int j = 0; j < 4; ++j) {
            const int g0 = mr + lq * 4 + j;
            const int g1 = mr + 16 + lq * 4 + j;
            if (g0 < NN) out[(size_t)g0 * 128 + n * 16 + lm] = fmaxf(acc0[n][j] + bias, 0.f);
            if (g1 < NN) out[(size_t)g1 * 128 + n * 16 + lm] = fmaxf(acc1[n][j] + bias, 0.f);
        }
    }
}

extern "C" void kernel_launch(void* const* d_in, const int* in_sizes, int n_in,
                              void* d_out, int out_size, void* d_ws, size_t ws_size,
                              hipStream_t stream)
{
    const float* x         = (const float*)d_in[0];
    const float* edge_attr = (const float*)d_in[1];
    const float* W_rel     = (const float*)d_in[2];
    const float* We_rel    = (const float*)d_in[3];
    const float* W_self    = (const float*)d_in[4];
    const float* b         = (const float*)d_in[5];
    const int*   edge_index= (const int*)d_in[6];
    float* out = (float*)d_out;

    // ws layout (bytes)
    char* wsb = (char*)d_ws;
    unsigned short* xb    = (unsigned short*)wsb;                    //  25,600,000
    unsigned short* Sb    = (unsigned short*)(wsb + 25600000);       //  76,800,000
    unsigned short* eagg  = (unsigned short*)(wsb + 102400000);      //  12,800,000
    unsigned short* Wtall = (unsigned short*)(wsb + 115200000);      //     147,456
    unsigned*       cur   = (unsigned*)(wsb + 115347456);            //     400,000
    unsigned*       offs  = (unsigned*)(wsb + 115747456);            //     400,004
    unsigned*       bsum  = (unsigned*)(wsb + 116147464);            //         512
    uint2*          elist = (uint2*)(wsb + 116147976);               //   4,800,000

    conv_x_kernel<<<NN * DN / 4 / 256, 256, 0, stream>>>(x, xb);
    conv_w_kernel<<<(128 * KTOT + 255) / 256, 256, 0, stream>>>(W_self, W_rel, We_rel, Wtall);

    hipMemsetAsync(cur, 0, NN * sizeof(unsigned), stream);
    const int eblocks = (NEDGE + 255) / 256;
    hist_kernel <<<eblocks, 256, 0, stream>>>(edge_index, cur);
    scan1_kernel<<<NB1, 256, 0, stream>>>(cur, offs, bsum);
    scan2_kernel<<<1, 64, 0, stream>>>(bsum);
    scan3_kernel<<<NB1, 256, 0, stream>>>(offs, cur, bsum);
    fill_kernel <<<eblocks, 256, 0, stream>>>(edge_index, cur, elist);

    aggregate_kernel<<<NN / 4, 256, 0, stream>>>(xb, edge_attr, offs, elist,
                                                 Sb, eagg);

    gemm_out_kernel<<<(NN + 127) / 128, 256, 0, stream>>>(xb, Sb, eagg, Wtall,
                                                          b, out);
}